// Round 13
// baseline (2039.486 us; speedup 1.0000x reference)
//
#include <hip/hip_runtime.h>

#define Hh 64
#define Tt 2048
#define Bb 256
#define NL 3

typedef _Float16 h2 __attribute__((ext_vector_type(2)));

__device__ __forceinline__ h2 uh2(unsigned u) { union { unsigned u; h2 h; } d; d.u = u; return d.h; }
#define FDOT2(a, b, c) __builtin_amdgcn_fdot2((a), (b), (c), false)

__device__ __forceinline__ float fast_sigmoid(float x) {
    return 1.0f / (1.0f + __expf(-x));
}
__device__ __forceinline__ float fast_tanh(float x) {
    float e = __expf(2.0f * x);
    return 1.0f - 2.0f / (e + 1.0f);
}

#define REPEAT16(M) M(0) M(1) M(2) M(3) M(4) M(5) M(6) M(7) \
                    M(8) M(9) M(10) M(11) M(12) M(13) M(14) M(15)

// ---- prepass 1: fp32 -> fp16 weight convert ----
__global__ void conv_w(const float* __restrict__ src, _Float16* __restrict__ dst, int n) {
    int i = blockIdx.x * 256 + threadIdx.x;
    if (i < n) dst[i] = (_Float16)src[i];
}

// ---- prepass 2: x [B,H,T] fp32 -> xh [B,T,H] fp16 (64x64 LDS tile transpose) ----
__global__ __launch_bounds__(256)
void prep_x(const float* __restrict__ x, _Float16* __restrict__ xh) {
    __shared__ float tile[64][65];
    const int b = blockIdx.x, tc = blockIdx.y;
    const int tt = threadIdx.x & 63, hq = threadIdx.x >> 6;
    const long xb = (long)b * Hh * Tt;
#pragma unroll
    for (int k = 0; k < 16; ++k) {
        const int h = hq * 16 + k;
        tile[h][tt] = x[xb + (long)h * Tt + tc * 64 + tt];
    }
    __syncthreads();
    _Float16* dst = xh + ((long)b * Tt + tc * 64 + tt) * Hh + hq * 16;
#pragma unroll
    for (int k = 0; k < 16; ++k) dst[k] = (_Float16)tile[hq * 16 + k][tt];
}

// ---- main: 12 waves/block, 4 per layer, layers pipelined with skew 1 ----
// Wave (l, s, uh); lane (kh, jj). Each lane: 3 half-rows of packed f16 = 48
// dwords + ~28 working regs.
//
// R3-R12 lesson: every attribute/asm pin failed because rematerializing an
// INVARIANT load is free in the compiler's cost model -- the scheduler sinks
// the weight loads into the loop and re-streams 147KB/block/phase from L2
// (~2600 cyc/phase = the whole runtime). Fix: VOLATILE weight loads. LLVM
// may not duplicate/sink/remat a volatile load -- hard semantics, not a
// heuristic. After the one-time pre-loop load, the in-loop defs are
// non-recomputable register values; demand (~76) fits even the stingiest
// observed cap (84), so keep-live is the allocator's only cheap option.
__global__
__attribute__((amdgpu_flat_work_group_size(768, 768)))
__attribute__((amdgpu_waves_per_eu(3, 3)))
void gru_pipe(const _Float16* __restrict__ xh, float* __restrict__ out,
              const _Float16* __restrict__ wih16, const _Float16* __restrict__ whh16,
              const float* __restrict__ bih, const float* __restrict__ bhh)
{
    const int b   = blockIdx.x;
    const int tid = threadIdx.x;
    const int w   = tid >> 6;        // 0..11
    const int l   = w >> 2;          // layer 0..2
    const int s   = (w >> 1) & 1;    // role
    const int uh  = w & 1;           // unit half
    const int ln  = tid & 63;
    const int kh  = ln >> 5;         // k half
    const int jj  = ln & 31;
    const int j   = uh * 32 + jj;    // hidden unit

    const int gA = s ? 64 + j : j;
    // volatile dword views of the three packed-f16 half-rows
    const volatile unsigned* pa =
        (const volatile unsigned*)((const h2*)wih16 + ((long)l * 192 + gA) * 32 + kh * 16);
    const volatile unsigned* pb =
        (const volatile unsigned*)((const h2*)whh16 + ((long)l * 192 + gA) * 32 + kh * 16);
    const volatile unsigned* pc =
        (const volatile unsigned*)((const h2*)(s ? wih16 : whh16) + ((long)l * 192 + 128 + j) * 32 + kh * 16);

    // One-time VOLATILE loads: cannot be rematerialized into the loop.
#define LW(k) h2 A##k = uh2(pa[k]); h2 B##k = uh2(pb[k]); h2 C##k = uh2(pc[k]);
    REPEAT16(LW)
#undef LW

    float bA = 0.0f, bC = 0.0f;
    if (kh == 0) {
        bA = bih[l*192 + gA] + bhh[l*192 + gA];
        bC = s ? bih[l*192 + 128 + j] : bhh[l*192 + 128 + j];
    }

    __shared__ __align__(16) _Float16 hbuf[NL][2][Hh]; // per-layer h, dbuf by parity
    __shared__ __align__(16) _Float16 xbuf[2][Hh];     // layer-0 input, dbuf
    __shared__ float ubuf[NL][Hh];                     // r*(Whh_n.h + bhn), fp32
    __shared__ float obuf[2][32][33];                  // layer-2 out staging, +1 pad

    const long ib  = (long)b * Hh * Tt;   // [B,H,T] out base
    const long ibh = (long)b * Tt * Hh;   // [B,T,H] xh base

    if (tid < NL * 2 * Hh) ((_Float16*)hbuf)[tid] = (_Float16)0.0f;
    float hprev = 0.0f;
    _Float16 xcur = (_Float16)0.0f, xnext = (_Float16)0.0f;  // wave 8 duty
    if (w == 8) {
        xbuf[0][ln] = xh[ibh + 0 * Hh + ln];
        xcur        = xh[ibh + 1 * Hh + ln];
    }
    __syncthreads();

    const uint4* xsA = (const uint4*)((l == 0) ? xbuf[0] : hbuf[l - 1][0]) + kh * 4;
    const uint4* xsB = (const uint4*)((l == 0) ? xbuf[1] : hbuf[l - 1][1]) + kh * 4;
    const uint4* hsA = (const uint4*)hbuf[l][0] + kh * 4;
    const uint4* hsB = (const uint4*)hbuf[l][1] + kh * 4;

    for (int p = 0; p < Tt + NL - 1; ++p) {
        const int rd = p & 1;
        const int t  = p - l;
        const bool act = (t >= 0) && (t < Tt);

        if (w == 8 && p + 2 < Tt) xnext = xh[ibh + (long)(p + 2) * Hh + ln];

        float accA = bA, accB = 0.0f, accC = bC;
        float zg = 0.0f;
        if (act) {
            const uint4* xs4 = rd ? xsB : xsA;
            const uint4* hs4 = rd ? hsB : hsA;
#define QSTEP(q, k0, k1, k2, k3, S3)  { \
    const uint4 X = xs4[q]; const uint4 Hv = hs4[q]; \
    accA = FDOT2(A##k0, uh2(X.x), accA); accB = FDOT2(B##k0, uh2(Hv.x), accB); accC = FDOT2(C##k0, uh2(S3.x), accC); \
    accA = FDOT2(A##k1, uh2(X.y), accA); accB = FDOT2(B##k1, uh2(Hv.y), accB); accC = FDOT2(C##k1, uh2(S3.y), accC); \
    accA = FDOT2(A##k2, uh2(X.z), accA); accB = FDOT2(B##k2, uh2(Hv.z), accB); accC = FDOT2(C##k2, uh2(S3.z), accC); \
    accA = FDOT2(A##k3, uh2(X.w), accA); accB = FDOT2(B##k3, uh2(Hv.w), accB); accC = FDOT2(C##k3, uh2(S3.w), accC); }
            if (s == 0) {
                QSTEP(0,  0,  1,  2,  3, Hv)
                QSTEP(1,  4,  5,  6,  7, Hv)
                QSTEP(2,  8,  9, 10, 11, Hv)
                QSTEP(3, 12, 13, 14, 15, Hv)
            } else {
                QSTEP(0,  0,  1,  2,  3, X)
                QSTEP(1,  4,  5,  6,  7, X)
                QSTEP(2,  8,  9, 10, 11, X)
                QSTEP(3, 12, 13, 14, 15, X)
            }
#undef QSTEP
            accA += __shfl_xor(accA, 32);
            accB += __shfl_xor(accB, 32);
            accC += __shfl_xor(accC, 32);
            const float g = fast_sigmoid(accA + accB);   // r (s=0) or z (s=1)
            if (s == 0) {
                if (kh == 0) ubuf[l][j] = g * accC;      // u = r*(Whh_n.h + bhn)
            }
            zg = g;
        }
        __syncthreads();   // B1: u visible

        if (act && s == 1) {
            const float n = fast_tanh(accC + ubuf[l][j]);   // accC = Wih_n.x + bxn
            const float hnew = fmaf(zg, hprev - n, n);      // (1-z)*n + z*h
            hprev = hnew;
            if (kh == 0) {
                hbuf[l][rd ^ 1][j] = (_Float16)hnew;
                if (l == NL - 1) obuf[uh][jj][t & 31] = hnew;
            }
        }
        if (w == 8) {
            if (p + 1 < Tt) xbuf[rd ^ 1][ln] = xcur;
            xcur = xnext;
        }
        __syncthreads();   // B2: h/x published for next phase

        if ((w >> 1) == 5 && act && (t & 31) == 31) {
            const float* srow = obuf[uh][jj] + kh * 16;
            float4* dst = (float4*)(out + ib + (long)j * Tt + (t - 31) + kh * 16);
            dst[0] = make_float4(srow[0],  srow[1],  srow[2],  srow[3]);
            dst[1] = make_float4(srow[4],  srow[5],  srow[6],  srow[7]);
            dst[2] = make_float4(srow[8],  srow[9],  srow[10], srow[11]);
            dst[3] = make_float4(srow[12], srow[13], srow[14], srow[15]);
        }
    }
}

extern "C" void kernel_launch(void* const* d_in, const int* in_sizes, int n_in,
                              void* d_out, int out_size, void* d_ws, size_t ws_size,
                              hipStream_t stream) {
    const float* x   = (const float*)d_in[0];   // [B, H, T]
    const float* Wih = (const float*)d_in[1];   // [3, 192, 64]
    const float* Whh = (const float*)d_in[2];   // [3, 192, 64]
    const float* bih = (const float*)d_in[3];   // [3, 192]
    const float* bhh = (const float*)d_in[4];   // [3, 192]
    float* out = (float*)d_out;                 // [B, H, T]

    _Float16* xh    = (_Float16*)d_ws;
    _Float16* wih16 = (_Float16*)((char*)d_ws + 67108864);
    _Float16* whh16 = (_Float16*)((char*)d_ws + 67108864 + 73728);
    const int nW = NL * 192 * 64;  // 36864

    conv_w<<<(nW + 255) / 256, 256, 0, stream>>>(Wih, wih16, nW);
    conv_w<<<(nW + 255) / 256, 256, 0, stream>>>(Whh, whh16, nW);
    prep_x<<<dim3(Bb, Tt / 64), 256, 0, stream>>>(x, xh);
    gru_pipe<<<Bb, 768, 0, stream>>>(xh, out, wih16, whh16, bih, bhh);
}